// Round 4
// baseline (488.511 us; speedup 1.0000x reference)
//
#include <hip/hip_runtime.h>
#include <cmath>

static constexpr int NN = 100000;   // nodes
static constexpr int NE = 1600000;  // edges
static const size_t NW = (size_t)NN * 32;
static constexpr int NSLICE = 8;            // dst slices ~ XCDs
static constexpr int SLICE_W = 12500;       // NN / NSLICE
static constexpr int FILL_BPG = 256;        // blocks per slice group

// ---------------------------------------------------------------------------
// CSR build: histogram of dst, exclusive scan, XCD-sliced fill.
// ---------------------------------------------------------------------------
__global__ void __launch_bounds__(256) hist_k(const int* __restrict__ dst,
                                              int* __restrict__ deg)
{
    unsigned e = blockIdx.x * 256u + threadIdx.x;
    if (e < (unsigned)NE) atomicAdd(deg + __builtin_nontemporal_load(dst + e), 1);
}

__global__ void __launch_bounds__(256) block_sum_k(const int* __restrict__ deg,
                                                   int* __restrict__ bsum)
{
    int n = blockIdx.x * 256 + threadIdx.x;
    int d = (n < NN) ? deg[n] : 0;
#pragma unroll
    for (int k = 32; k; k >>= 1) d += __shfl_xor(d, k, 64);
    __shared__ int s[4];
    if ((threadIdx.x & 63) == 0) s[threadIdx.x >> 6] = d;
    __syncthreads();
    if (threadIdx.x == 0) bsum[blockIdx.x] = s[0] + s[1] + s[2] + s[3];
}

__global__ void __launch_bounds__(512) scan_bsum_k(const int* __restrict__ bsum,
                                                   int np, int* __restrict__ ebase)
{
    __shared__ int tmp[512];
    int t = threadIdx.x;
    int v = (t < np) ? bsum[t] : 0;
    tmp[t] = v;
    __syncthreads();
    for (int s = 1; s < 512; s <<= 1) {
        int x = tmp[t];
        int add = (t >= s) ? tmp[t - s] : 0;
        __syncthreads();
        tmp[t] = x + add;
        __syncthreads();
    }
    if (t < np) ebase[t] = tmp[t] - v;
}

__global__ void __launch_bounds__(256) scan_write_k(const int* __restrict__ deg,
                                                    const int* __restrict__ ebase,
                                                    int* __restrict__ off,
                                                    int* __restrict__ cursor)
{
    __shared__ int tmp[256];
    int t = threadIdx.x;
    int n = blockIdx.x * 256 + t;
    int d = (n < NN) ? deg[n] : 0;
    tmp[t] = d;
    __syncthreads();
    for (int s = 1; s < 256; s <<= 1) {
        int x = tmp[t];
        int add = (t >= s) ? tmp[t - s] : 0;
        __syncthreads();
        tmp[t] = x + add;
        __syncthreads();
    }
    int excl = tmp[t] - d;
    if (n < NN) {
        int base = ebase[blockIdx.x] + excl;
        off[n] = base;
        cursor[n] = base;
    }
}

// XCD-sliced fill with NON-TEMPORAL streaming reads: group g (= blockIdx%8,
// dispatch round-robin ~ one XCD) writes only csr entries for dst in its
// slice. nt loads keep the dst/src/ew streams from evicting the dirty csr
// lines out of the XCD's L2, so each csr line is written back once, full.
__global__ void __launch_bounds__(256) fill2_k(const int* __restrict__ src,
                                               const int* __restrict__ dst,
                                               const float* __restrict__ ew,
                                               int* __restrict__ cursor,
                                               int2* __restrict__ csr)
{
    int g = blockIdx.x & (NSLICE - 1);
    int b = blockIdx.x >> 3;
    int lo = g * SLICE_W, hi = lo + SLICE_W;
    for (int e = b * 256 + (int)threadIdx.x; e < NE; e += FILL_BPG * 256) {
        int d = __builtin_nontemporal_load(dst + e);
        if (d < lo || d >= hi) continue;
        int pos = atomicAdd(cursor + d, 1);
        int2 pk;
        pk.x = __builtin_nontemporal_load(src + e);
        pk.y = __float_as_int(__builtin_nontemporal_load(ew + e));
        csr[pos] = pk;
    }
}

// ---------------------------------------------------------------------------
// proj = in @ W  (W: [K,32] in LDS). 8 nodes/block, lane j owns col j.
// ---------------------------------------------------------------------------
template <int K>
__global__ void __launch_bounds__(256) matmul_k(const float* __restrict__ in,
                                                const float* __restrict__ W,
                                                float* __restrict__ out)
{
    __shared__ float sW[K * 32];
    for (int i = threadIdx.x; i < K * 32; i += 256) sW[i] = W[i];
    __syncthreads();
    int n = blockIdx.x * 8 + (threadIdx.x >> 5);
    int j = threadIdx.x & 31;
    const float* row = in + (size_t)n * K;
    float acc = 0.f;
#pragma unroll
    for (int k = 0; k < K; ++k) acc = fmaf(row[k], sW[k * 32 + j], acc);
    out[(size_t)n * 32 + j] = acc;
}

// ---------------------------------------------------------------------------
// Gather-aggregate layer: h_out[n] = relu( sum_e w_e*proj[src_e] + b + x@Wroot )
// csr stream read non-temporally so it doesn't evict proj rows from L2.
// ---------------------------------------------------------------------------
template <int K>
__global__ void __launch_bounds__(256) agg_root_relu_k(
    const float* __restrict__ proj, const float* __restrict__ xin,
    const float* __restrict__ Wroot, const float* __restrict__ bias,
    const long long* __restrict__ csr, const int* __restrict__ off,
    const int* __restrict__ deg, float* __restrict__ hout)
{
    __shared__ float sW[K * 32];
    for (int i = threadIdx.x; i < K * 32; i += 256) sW[i] = Wroot[i];
    __syncthreads();
    int n = blockIdx.x * 8 + (threadIdx.x >> 5);
    int j = threadIdx.x & 31;
    int st = off[n], dg = deg[n];
    float acc = 0.f;
    int i = 0;
    for (; i + 3 < dg; i += 4) {
        long long r0 = __builtin_nontemporal_load(csr + st + i);
        long long r1 = __builtin_nontemporal_load(csr + st + i + 1);
        long long r2 = __builtin_nontemporal_load(csr + st + i + 2);
        long long r3 = __builtin_nontemporal_load(csr + st + i + 3);
        float a0 = proj[(size_t)(int)r0 * 32 + j];
        float a1 = proj[(size_t)(int)r1 * 32 + j];
        float a2 = proj[(size_t)(int)r2 * 32 + j];
        float a3 = proj[(size_t)(int)r3 * 32 + j];
        acc = fmaf(a0, __int_as_float((int)(r0 >> 32)), acc);
        acc = fmaf(a1, __int_as_float((int)(r1 >> 32)), acc);
        acc = fmaf(a2, __int_as_float((int)(r2 >> 32)), acc);
        acc = fmaf(a3, __int_as_float((int)(r3 >> 32)), acc);
    }
    for (; i < dg; ++i) {
        long long r0 = __builtin_nontemporal_load(csr + st + i);
        acc = fmaf(proj[(size_t)(int)r0 * 32 + j], __int_as_float((int)(r0 >> 32)), acc);
    }
    const float* row = xin + (size_t)n * K;
    float r = 0.f;
#pragma unroll
    for (int k = 0; k < K; ++k) r = fmaf(row[k], sW[k * 32 + j], r);
    float v = acc + bias[j] + r;
    hout[(size_t)n * 32 + j] = v > 0.f ? v : 0.f;
}

// ---------------------------------------------------------------------------
// Layer-2 aggregate + inline root + ReLU + all four OUT=1 head projections.
// ---------------------------------------------------------------------------
__global__ void __launch_bounds__(256) agg2_heads_k(
    const float* __restrict__ proj, const float* __restrict__ h1,
    const float* __restrict__ Wroot, const float* __restrict__ bias,
    const float* __restrict__ Wp_rel, const float* __restrict__ Wp_root,
    const float* __restrict__ bp, const float* __restrict__ Wv_rel,
    const float* __restrict__ Wv_root, const float* __restrict__ bv,
    const long long* __restrict__ csr, const int* __restrict__ off,
    const int* __restrict__ deg, float2* __restrict__ pv,
    float* __restrict__ pbase, float* __restrict__ vbase)
{
    __shared__ float sW[32 * 32];
    __shared__ float sHead[4 * 32];
    for (int i = threadIdx.x; i < 32 * 32; i += 256) sW[i] = Wroot[i];
    if (threadIdx.x < 32) {
        sHead[threadIdx.x] = Wp_rel[threadIdx.x];
        sHead[32 + threadIdx.x] = Wp_root[threadIdx.x];
        sHead[64 + threadIdx.x] = Wv_rel[threadIdx.x];
        sHead[96 + threadIdx.x] = Wv_root[threadIdx.x];
    }
    __syncthreads();
    int n = blockIdx.x * 8 + (threadIdx.x >> 5);
    int j = threadIdx.x & 31;
    int st = off[n], dg = deg[n];
    float acc = 0.f;
    int i = 0;
    for (; i + 3 < dg; i += 4) {
        long long r0 = __builtin_nontemporal_load(csr + st + i);
        long long r1 = __builtin_nontemporal_load(csr + st + i + 1);
        long long r2 = __builtin_nontemporal_load(csr + st + i + 2);
        long long r3 = __builtin_nontemporal_load(csr + st + i + 3);
        float a0 = proj[(size_t)(int)r0 * 32 + j];
        float a1 = proj[(size_t)(int)r1 * 32 + j];
        float a2 = proj[(size_t)(int)r2 * 32 + j];
        float a3 = proj[(size_t)(int)r3 * 32 + j];
        acc = fmaf(a0, __int_as_float((int)(r0 >> 32)), acc);
        acc = fmaf(a1, __int_as_float((int)(r1 >> 32)), acc);
        acc = fmaf(a2, __int_as_float((int)(r2 >> 32)), acc);
        acc = fmaf(a3, __int_as_float((int)(r3 >> 32)), acc);
    }
    for (; i < dg; ++i) {
        long long r0 = __builtin_nontemporal_load(csr + st + i);
        acc = fmaf(proj[(size_t)(int)r0 * 32 + j], __int_as_float((int)(r0 >> 32)), acc);
    }
    const float* row = h1 + (size_t)n * 32;
    float r = 0.f;
#pragma unroll
    for (int k = 0; k < 32; ++k) r = fmaf(row[k], sW[k * 32 + j], r);
    float hv = acc + bias[j] + r;
    hv = hv > 0.f ? hv : 0.f;
    float prv = hv * sHead[j];
    float pov = hv * sHead[32 + j];
    float vrv = hv * sHead[64 + j];
    float vov = hv * sHead[96 + j];
#pragma unroll
    for (int m = 16; m; m >>= 1) {
        prv += __shfl_xor(prv, m, 32);
        pov += __shfl_xor(pov, m, 32);
        vrv += __shfl_xor(vrv, m, 32);
        vov += __shfl_xor(vov, m, 32);
    }
    if (j == 0) {
        pv[n] = make_float2(prv, vrv);
        pbase[n] = pov + bp[0];
        vbase[n] = vov + bv[0];
    }
}

// ---------------------------------------------------------------------------
// Per-node head aggregation + legal-move mask + masked outputs + block max.
// ---------------------------------------------------------------------------
__global__ void __launch_bounds__(256) heads_final_k(
    const float2* __restrict__ pv, const float* __restrict__ pbase,
    const float* __restrict__ vbase, const long long* __restrict__ csr,
    const int* __restrict__ off, const int* __restrict__ deg,
    const int* __restrict__ curp, float* __restrict__ pm,
    float* __restrict__ out_v, float* __restrict__ partials)
{
    int n = blockIdx.x * 256 + threadIdx.x;
    int cur = curp[0];
    float pmv = -INFINITY;
    if (n < NN) {
        int st = off[n], dg = deg[n];
        float pa = 0.f, va = 0.f, m = 0.f;
        for (int i = 0; i < dg; ++i) {
            long long r0 = __builtin_nontemporal_load(csr + st + i);
            int s = (int)r0;
            float2 t = pv[s];
            float w = __int_as_float((int)(r0 >> 32));
            pa = fmaf(t.x, w, pa);
            va = fmaf(t.y, w, va);
            if (s == cur) m = 1.f;
        }
        float p = pa + pbase[n];
        float v = va + vbase[n];
        float pm0 = m * p;
        pmv = (pm0 == 0.f) ? -INFINITY : pm0;  // jnp.where(p_m==0, -inf, p_m)
        pm[n] = pmv;
        out_v[n] = m * v;
    }
    __shared__ float smax[4];
    float wm = pmv;
#pragma unroll
    for (int k = 32; k; k >>= 1) wm = fmaxf(wm, __shfl_xor(wm, k, 64));
    if ((threadIdx.x & 63) == 0) smax[threadIdx.x >> 6] = wm;
    __syncthreads();
    if (threadIdx.x == 0)
        partials[blockIdx.x] = fmaxf(fmaxf(smax[0], smax[1]), fmaxf(smax[2], smax[3]));
}

__global__ void __launch_bounds__(256) reduce_max_k(
    const float* __restrict__ partials, int np, float* __restrict__ scal)
{
    float m = -INFINITY;
    for (int i = threadIdx.x; i < np; i += 256) m = fmaxf(m, partials[i]);
    __shared__ float s[4];
#pragma unroll
    for (int k = 32; k; k >>= 1) m = fmaxf(m, __shfl_xor(m, k, 64));
    if ((threadIdx.x & 63) == 0) s[threadIdx.x >> 6] = m;
    __syncthreads();
    if (threadIdx.x == 0) {
        scal[0] = fmaxf(fmaxf(s[0], s[1]), fmaxf(s[2], s[3]));
        scal[1] = 0.f;
    }
}

__global__ void __launch_bounds__(256) expsum_k(const float* __restrict__ pm,
                                                float* __restrict__ scal,
                                                float* __restrict__ ev)
{
    int n = blockIdx.x * 256 + threadIdx.x;
    float e = 0.f;
    if (n < NN) {
        float x = pm[n];
        e = (x == -INFINITY) ? 0.f : expf(x - scal[0]);
        ev[n] = e;
    }
    __shared__ float s[4];
    float ws = e;
#pragma unroll
    for (int k = 32; k; k >>= 1) ws += __shfl_xor(ws, k, 64);
    if ((threadIdx.x & 63) == 0) s[threadIdx.x >> 6] = ws;
    __syncthreads();
    if (threadIdx.x == 0) atomicAdd(scal + 1, s[0] + s[1] + s[2] + s[3]);
}

__global__ void __launch_bounds__(256) normalize_k(const float* __restrict__ ev,
                                                   const float* __restrict__ scal,
                                                   float* __restrict__ out)
{
    int n = blockIdx.x * 256 + threadIdx.x;
    if (n < NN) out[n] = ev[n] / scal[1];
}

// ---------------------------------------------------------------------------
extern "C" void kernel_launch(void* const* d_in, const int* in_sizes, int n_in,
                              void* d_out, int out_size, void* d_ws,
                              size_t ws_size, hipStream_t stream)
{
    const float* x        = (const float*)d_in[0];
    const int*   ei       = (const int*)d_in[1];   // [2,E] row-major
    const float* ew       = (const float*)d_in[2];
    const int*   cur      = (const int*)d_in[3];
    const float* Win_rel  = (const float*)d_in[4];
    const float* bin_rel  = (const float*)d_in[5];
    const float* Win_root = (const float*)d_in[6];
    const float* Wh_rel   = (const float*)d_in[7];
    const float* bh_rel   = (const float*)d_in[8];
    const float* Wh_root  = (const float*)d_in[9];
    const float* Wp_rel   = (const float*)d_in[10];
    const float* bp       = (const float*)d_in[11];
    const float* Wp_root  = (const float*)d_in[12];
    const float* Wv_rel   = (const float*)d_in[13];
    const float* bv       = (const float*)d_in[14];
    const float* Wv_root  = (const float*)d_in[15];

    const int* srcA = ei;
    const int* dstA = ei + NE;

    char* w8 = (char*)d_ws;
    int2* csr   = (int2*)w8;                 // 12.8 MB
    int* deg    = (int*)(csr + NE);          // 400 KB
    int* off    = deg + NN;
    int* cursor = off + NN;
    int* bsum   = cursor + NN;               // 512 ints
    int* ebase  = bsum + 512;                // 512 ints
    float* A    = (float*)(ebase + 512);     // 12.8 MB  (proj1 / proj2)
    float* H    = A + NW;                    // 12.8 MB  (h1)
    float2* pv  = (float2*)(H + NW);         // 800 KB
    float* pbase = (float*)(pv + NN);        // 400 KB
    float* vbase = pbase + NN;               // 400 KB
    // aliases into A (free after agg2_heads_k):
    float* pm    = A;
    float* ev    = A + NN;
    float* parts = A + 2 * (size_t)NN;       // 391
    float* scal  = parts + 512;

    const long long* csr64 = (const long long*)csr;

    float* out_p = (float*)d_out;
    float* out_v = out_p + NN;

    const int NB_N   = (NN + 255) / 256;  // 391
    const int NB_E   = (NE + 255) / 256;  // 6250
    const int NB_NOD = NN / 8;            // 12500 (exact)

    // --- CSR build ---
    hipMemsetAsync(deg, 0, NN * sizeof(int), stream);
    hist_k<<<NB_E, 256, 0, stream>>>(dstA, deg);
    block_sum_k<<<NB_N, 256, 0, stream>>>(deg, bsum);
    scan_bsum_k<<<1, 512, 0, stream>>>(bsum, NB_N, ebase);
    scan_write_k<<<NB_N, 256, 0, stream>>>(deg, ebase, off, cursor);
    fill2_k<<<NSLICE * FILL_BPG, 256, 0, stream>>>(srcA, dstA, ew, cursor, csr);

    // --- Layer 1 ---
    matmul_k<64><<<NB_NOD, 256, 0, stream>>>(x, Win_rel, A);
    agg_root_relu_k<64><<<NB_NOD, 256, 0, stream>>>(A, x, Win_root, bin_rel,
                                                    csr64, off, deg, H);
    // --- Layer 2 + heads ---
    matmul_k<32><<<NB_NOD, 256, 0, stream>>>(H, Wh_rel, A);
    agg2_heads_k<<<NB_NOD, 256, 0, stream>>>(A, H, Wh_root, bh_rel, Wp_rel,
                                             Wp_root, bp, Wv_rel, Wv_root, bv,
                                             csr64, off, deg, pv, pbase, vbase);
    // --- Head aggregation + mask + finalize ---
    heads_final_k<<<NB_N, 256, 0, stream>>>(pv, pbase, vbase, csr64, off, deg,
                                            cur, pm, out_v, parts);
    reduce_max_k<<<1, 256, 0, stream>>>(parts, NB_N, scal);
    expsum_k<<<NB_N, 256, 0, stream>>>(pm, scal, ev);
    normalize_k<<<NB_N, 256, 0, stream>>>(ev, scal, out_p);
}

// Round 5
// 461.258 us; speedup vs baseline: 1.0591x; 1.0591x over previous
//
#include <hip/hip_runtime.h>
#include <cmath>

static constexpr int NN = 100000;   // nodes
static constexpr int NE = 1600000;  // edges
static const size_t NW = (size_t)NN * 32;
static constexpr int NSLICE = 8;            // dst slices ~ XCDs
static constexpr int SLICE_W = 12500;       // NN / NSLICE
static constexpr int FILL_BPG = 256;        // blocks per slice group

// ---------------------------------------------------------------------------
// CSR build: histogram of dst, exclusive scan, XCD-sliced fill.
// ---------------------------------------------------------------------------
__global__ void __launch_bounds__(256) hist_k(const int* __restrict__ dst,
                                              int* __restrict__ deg)
{
    unsigned e = blockIdx.x * 256u + threadIdx.x;
    if (e < (unsigned)NE) atomicAdd(deg + dst[e], 1);
}

__global__ void __launch_bounds__(256) block_sum_k(const int* __restrict__ deg,
                                                   int* __restrict__ bsum)
{
    int n = blockIdx.x * 256 + threadIdx.x;
    int d = (n < NN) ? deg[n] : 0;
#pragma unroll
    for (int k = 32; k; k >>= 1) d += __shfl_xor(d, k, 64);
    __shared__ int s[4];
    if ((threadIdx.x & 63) == 0) s[threadIdx.x >> 6] = d;
    __syncthreads();
    if (threadIdx.x == 0) bsum[blockIdx.x] = s[0] + s[1] + s[2] + s[3];
}

__global__ void __launch_bounds__(512) scan_bsum_k(const int* __restrict__ bsum,
                                                   int np, int* __restrict__ ebase)
{
    __shared__ int tmp[512];
    int t = threadIdx.x;
    int v = (t < np) ? bsum[t] : 0;
    tmp[t] = v;
    __syncthreads();
    for (int s = 1; s < 512; s <<= 1) {
        int x = tmp[t];
        int add = (t >= s) ? tmp[t - s] : 0;
        __syncthreads();
        tmp[t] = x + add;
        __syncthreads();
    }
    if (t < np) ebase[t] = tmp[t] - v;
}

__global__ void __launch_bounds__(256) scan_write_k(const int* __restrict__ deg,
                                                    const int* __restrict__ ebase,
                                                    int* __restrict__ off,
                                                    int* __restrict__ cursor)
{
    __shared__ int tmp[256];
    int t = threadIdx.x;
    int n = blockIdx.x * 256 + t;
    int d = (n < NN) ? deg[n] : 0;
    tmp[t] = d;
    __syncthreads();
    for (int s = 1; s < 256; s <<= 1) {
        int x = tmp[t];
        int add = (t >= s) ? tmp[t - s] : 0;
        __syncthreads();
        tmp[t] = x + add;
        __syncthreads();
    }
    int excl = tmp[t] - d;
    if (n < NN) {
        int base = ebase[blockIdx.x] + excl;
        off[n] = base;
        cursor[n] = base;
    }
}

// XCD-sliced fill (R3 version — no nt loads; nt was a measured regression).
__global__ void __launch_bounds__(256) fill2_k(const int* __restrict__ src,
                                               const int* __restrict__ dst,
                                               const float* __restrict__ ew,
                                               int* __restrict__ cursor,
                                               int2* __restrict__ csr)
{
    int g = blockIdx.x & (NSLICE - 1);
    int b = blockIdx.x >> 3;
    int lo = g * SLICE_W, hi = lo + SLICE_W;
    for (int e = b * 256 + (int)threadIdx.x; e < NE; e += FILL_BPG * 256) {
        int d = dst[e];
        if (d < lo || d >= hi) continue;
        int pos = atomicAdd(cursor + d, 1);
        int2 pk;
        pk.x = src[e];
        pk.y = __float_as_int(ew[e]);
        csr[pos] = pk;
    }
}

// ---------------------------------------------------------------------------
// proj = in @ W  (W: [K,32] in LDS). 8 nodes/block, lane j owns col j.
// ---------------------------------------------------------------------------
template <int K>
__global__ void __launch_bounds__(256) matmul_k(const float* __restrict__ in,
                                                const float* __restrict__ W,
                                                float* __restrict__ out)
{
    __shared__ float sW[K * 32];
    for (int i = threadIdx.x; i < K * 32; i += 256) sW[i] = W[i];
    __syncthreads();
    int n = blockIdx.x * 8 + (threadIdx.x >> 5);
    int j = threadIdx.x & 31;
    const float* row = in + (size_t)n * K;
    float acc = 0.f;
#pragma unroll
    for (int k = 0; k < K; ++k) acc = fmaf(row[k], sW[k * 32 + j], acc);
    out[(size_t)n * 32 + j] = acc;
}

// ---------------------------------------------------------------------------
// Wave-per-node gather-aggregate + inline root + ReLU.
// 64 lanes = 8 edge-slots (e_i) x 8 feature-quads (q); float4 gathers: one
// VMEM instruction fetches 8 random 128B proj rows. Root matmul folded into
// the same quad layout (k split over e_i; LDS weights transposed, +1 pad ->
// 2-way bank aliasing only, which is free). One xor-8/16/32 reduction
// finishes agg+root together; all lanes end up with the full quad sum.
// ---------------------------------------------------------------------------
template <int K>
__global__ void __launch_bounds__(256) agg_root_relu_v2(
    const float* __restrict__ proj, const float* __restrict__ xin,
    const float* __restrict__ Wroot, const float* __restrict__ bias,
    const long long* __restrict__ csr, const int* __restrict__ off,
    const int* __restrict__ deg, float* __restrict__ hout)
{
    __shared__ float sW[32 * (K + 1)];   // sW[f*(K+1)+k] = Wroot[k][f]
    for (int i = threadIdx.x; i < K * 32; i += 256) {
        int k = i >> 5, f = i & 31;
        sW[f * (K + 1) + k] = Wroot[i];
    }
    __syncthreads();
    int lane = threadIdx.x & 63;
    int e_i = lane >> 3;
    int q = lane & 7;
    int n = blockIdx.x * 4 + (threadIdx.x >> 6);   // NN % 4 == 0
    int st = off[n], dg = deg[n];
    float4 acc = make_float4(0.f, 0.f, 0.f, 0.f);
    for (int i = e_i; i < dg; i += 8) {
        long long ent = csr[st + i];
        int s = (int)ent;
        float w = __int_as_float((int)(ent >> 32));
        float4 row = *(const float4*)(proj + (size_t)s * 32 + q * 4);
        acc.x = fmaf(w, row.x, acc.x);
        acc.y = fmaf(w, row.y, acc.y);
        acc.z = fmaf(w, row.z, acc.z);
        acc.w = fmaf(w, row.w, acc.w);
    }
    const float* xrow = xin + (size_t)n * K;
#pragma unroll
    for (int t = 0; t < K / 8; ++t) {
        int k = 8 * t + e_i;
        float xv = xrow[k];
        const float* wp = sW + k;
        acc.x = fmaf(xv, wp[(q * 4 + 0) * (K + 1)], acc.x);
        acc.y = fmaf(xv, wp[(q * 4 + 1) * (K + 1)], acc.y);
        acc.z = fmaf(xv, wp[(q * 4 + 2) * (K + 1)], acc.z);
        acc.w = fmaf(xv, wp[(q * 4 + 3) * (K + 1)], acc.w);
    }
#pragma unroll
    for (int m = 8; m <= 32; m <<= 1) {
        acc.x += __shfl_xor(acc.x, m, 64);
        acc.y += __shfl_xor(acc.y, m, 64);
        acc.z += __shfl_xor(acc.z, m, 64);
        acc.w += __shfl_xor(acc.w, m, 64);
    }
    if (e_i == 0) {
        const float4 b4 = *(const float4*)(bias + q * 4);
        float4 o;
        o.x = fmaxf(acc.x + b4.x, 0.f);
        o.y = fmaxf(acc.y + b4.y, 0.f);
        o.z = fmaxf(acc.z + b4.z, 0.f);
        o.w = fmaxf(acc.w + b4.w, 0.f);
        *(float4*)(hout + (size_t)n * 32 + q * 4) = o;   // 8 lanes -> 128B
    }
}

// ---------------------------------------------------------------------------
// Layer-2 wave-per-node aggregate + inline root + ReLU + 4 head dots.
// Same structure as agg_root_relu_v2 (K=32); after the e_i reduction every
// lane holds the full h2 quad, so head dots reduce over q (xor 1,2,4).
// ---------------------------------------------------------------------------
__global__ void __launch_bounds__(256) agg2_heads_v2(
    const float* __restrict__ proj, const float* __restrict__ h1,
    const float* __restrict__ Wroot, const float* __restrict__ bias,
    const float* __restrict__ Wp_rel, const float* __restrict__ Wp_root,
    const float* __restrict__ bp, const float* __restrict__ Wv_rel,
    const float* __restrict__ Wv_root, const float* __restrict__ bv,
    const long long* __restrict__ csr, const int* __restrict__ off,
    const int* __restrict__ deg, float2* __restrict__ pv,
    float* __restrict__ pbase, float* __restrict__ vbase)
{
    constexpr int K = 32;
    __shared__ float sW[32 * (K + 1)];
    __shared__ float sHead[4 * 32];
    for (int i = threadIdx.x; i < K * 32; i += 256) {
        int k = i >> 5, f = i & 31;
        sW[f * (K + 1) + k] = Wroot[i];
    }
    if (threadIdx.x < 32) {
        sHead[threadIdx.x] = Wp_rel[threadIdx.x];
        sHead[32 + threadIdx.x] = Wp_root[threadIdx.x];
        sHead[64 + threadIdx.x] = Wv_rel[threadIdx.x];
        sHead[96 + threadIdx.x] = Wv_root[threadIdx.x];
    }
    __syncthreads();
    int lane = threadIdx.x & 63;
    int e_i = lane >> 3;
    int q = lane & 7;
    int n = blockIdx.x * 4 + (threadIdx.x >> 6);
    int st = off[n], dg = deg[n];
    float4 acc = make_float4(0.f, 0.f, 0.f, 0.f);
    for (int i = e_i; i < dg; i += 8) {
        long long ent = csr[st + i];
        int s = (int)ent;
        float w = __int_as_float((int)(ent >> 32));
        float4 row = *(const float4*)(proj + (size_t)s * 32 + q * 4);
        acc.x = fmaf(w, row.x, acc.x);
        acc.y = fmaf(w, row.y, acc.y);
        acc.z = fmaf(w, row.z, acc.z);
        acc.w = fmaf(w, row.w, acc.w);
    }
    const float* xrow = h1 + (size_t)n * K;
#pragma unroll
    for (int t = 0; t < K / 8; ++t) {
        int k = 8 * t + e_i;
        float xv = xrow[k];
        const float* wp = sW + k;
        acc.x = fmaf(xv, wp[(q * 4 + 0) * (K + 1)], acc.x);
        acc.y = fmaf(xv, wp[(q * 4 + 1) * (K + 1)], acc.y);
        acc.z = fmaf(xv, wp[(q * 4 + 2) * (K + 1)], acc.z);
        acc.w = fmaf(xv, wp[(q * 4 + 3) * (K + 1)], acc.w);
    }
#pragma unroll
    for (int m = 8; m <= 32; m <<= 1) {
        acc.x += __shfl_xor(acc.x, m, 64);
        acc.y += __shfl_xor(acc.y, m, 64);
        acc.z += __shfl_xor(acc.z, m, 64);
        acc.w += __shfl_xor(acc.w, m, 64);
    }
    const float4 b4 = *(const float4*)(bias + q * 4);
    float h0 = fmaxf(acc.x + b4.x, 0.f);
    float h1v = fmaxf(acc.y + b4.y, 0.f);
    float h2v = fmaxf(acc.z + b4.z, 0.f);
    float h3 = fmaxf(acc.w + b4.w, 0.f);
    int f0 = q * 4;
    float prv = h0 * sHead[f0] + h1v * sHead[f0 + 1] + h2v * sHead[f0 + 2] + h3 * sHead[f0 + 3];
    float pov = h0 * sHead[32 + f0] + h1v * sHead[33 + f0] + h2v * sHead[34 + f0] + h3 * sHead[35 + f0];
    float vrv = h0 * sHead[64 + f0] + h1v * sHead[65 + f0] + h2v * sHead[66 + f0] + h3 * sHead[67 + f0];
    float vov = h0 * sHead[96 + f0] + h1v * sHead[97 + f0] + h2v * sHead[98 + f0] + h3 * sHead[99 + f0];
#pragma unroll
    for (int m = 1; m <= 4; m <<= 1) {
        prv += __shfl_xor(prv, m, 64);
        pov += __shfl_xor(pov, m, 64);
        vrv += __shfl_xor(vrv, m, 64);
        vov += __shfl_xor(vov, m, 64);
    }
    if (lane == 0) {
        pv[n] = make_float2(prv, vrv);
        pbase[n] = pov + bp[0];
        vbase[n] = vov + bv[0];
    }
}

// ---------------------------------------------------------------------------
// Head aggregation + legal-move mask + masked outputs + block max.
// 8 edge-lanes per node (64 lanes = 8 nodes); xor-1/2/4 reduction.
// ---------------------------------------------------------------------------
__global__ void __launch_bounds__(256) heads_final_v2(
    const float2* __restrict__ pv, const float* __restrict__ pbase,
    const float* __restrict__ vbase, const long long* __restrict__ csr,
    const int* __restrict__ off, const int* __restrict__ deg,
    const int* __restrict__ curp, float* __restrict__ pm,
    float* __restrict__ out_v, float* __restrict__ partials)
{
    int lane = threadIdx.x & 63;
    int nsub = lane >> 3;
    int e_i = lane & 7;
    int n = blockIdx.x * 32 + (threadIdx.x >> 6) * 8 + nsub;   // NN % 32 == 0
    int cur = curp[0];
    int st = off[n], dg = deg[n];
    float pa = 0.f, va = 0.f, mk = 0.f;
    for (int i = e_i; i < dg; i += 8) {
        long long ent = csr[st + i];
        int s = (int)ent;
        float w = __int_as_float((int)(ent >> 32));
        float2 t = pv[s];
        pa = fmaf(t.x, w, pa);
        va = fmaf(t.y, w, va);
        if (s == cur) mk = 1.f;
    }
#pragma unroll
    for (int m = 1; m <= 4; m <<= 1) {
        pa += __shfl_xor(pa, m, 64);
        va += __shfl_xor(va, m, 64);
        mk = fmaxf(mk, __shfl_xor(mk, m, 64));
    }
    float pmv = -INFINITY;
    if (e_i == 0) {
        float p = pa + pbase[n];
        float v = va + vbase[n];
        float pm0 = mk * p;
        pmv = (pm0 == 0.f) ? -INFINITY : pm0;   // jnp.where(p_m==0,-inf,p_m)
        pm[n] = pmv;
        out_v[n] = mk * v;
    }
    __shared__ float smax[4];
    float wm = pmv;
#pragma unroll
    for (int k = 32; k; k >>= 1) wm = fmaxf(wm, __shfl_xor(wm, k, 64));
    if (lane == 0) smax[threadIdx.x >> 6] = wm;
    __syncthreads();
    if (threadIdx.x == 0)
        partials[blockIdx.x] = fmaxf(fmaxf(smax[0], smax[1]), fmaxf(smax[2], smax[3]));
}

__global__ void __launch_bounds__(256) reduce_max_k(
    const float* __restrict__ partials, int np, float* __restrict__ scal)
{
    float m = -INFINITY;
    for (int i = threadIdx.x; i < np; i += 256) m = fmaxf(m, partials[i]);
    __shared__ float s[4];
#pragma unroll
    for (int k = 32; k; k >>= 1) m = fmaxf(m, __shfl_xor(m, k, 64));
    if ((threadIdx.x & 63) == 0) s[threadIdx.x >> 6] = m;
    __syncthreads();
    if (threadIdx.x == 0) {
        scal[0] = fmaxf(fmaxf(s[0], s[1]), fmaxf(s[2], s[3]));
        scal[1] = 0.f;
    }
}

__global__ void __launch_bounds__(256) expsum_k(const float* __restrict__ pm,
                                                float* __restrict__ scal,
                                                float* __restrict__ ev)
{
    int n = blockIdx.x * 256 + threadIdx.x;
    float e = 0.f;
    if (n < NN) {
        float x = pm[n];
        e = (x == -INFINITY) ? 0.f : expf(x - scal[0]);
        ev[n] = e;
    }
    __shared__ float s[4];
    float ws = e;
#pragma unroll
    for (int k = 32; k; k >>= 1) ws += __shfl_xor(ws, k, 64);
    if ((threadIdx.x & 63) == 0) s[threadIdx.x >> 6] = ws;
    __syncthreads();
    if (threadIdx.x == 0) atomicAdd(scal + 1, s[0] + s[1] + s[2] + s[3]);
}

__global__ void __launch_bounds__(256) normalize_k(const float* __restrict__ ev,
                                                   const float* __restrict__ scal,
                                                   float* __restrict__ out)
{
    int n = blockIdx.x * 256 + threadIdx.x;
    if (n < NN) out[n] = ev[n] / scal[1];
}

// ---------------------------------------------------------------------------
extern "C" void kernel_launch(void* const* d_in, const int* in_sizes, int n_in,
                              void* d_out, int out_size, void* d_ws,
                              size_t ws_size, hipStream_t stream)
{
    const float* x        = (const float*)d_in[0];
    const int*   ei       = (const int*)d_in[1];   // [2,E] row-major
    const float* ew       = (const float*)d_in[2];
    const int*   cur      = (const int*)d_in[3];
    const float* Win_rel  = (const float*)d_in[4];
    const float* bin_rel  = (const float*)d_in[5];
    const float* Win_root = (const float*)d_in[6];
    const float* Wh_rel   = (const float*)d_in[7];
    const float* bh_rel   = (const float*)d_in[8];
    const float* Wh_root  = (const float*)d_in[9];
    const float* Wp_rel   = (const float*)d_in[10];
    const float* bp       = (const float*)d_in[11];
    const float* Wp_root  = (const float*)d_in[12];
    const float* Wv_rel   = (const float*)d_in[13];
    const float* bv       = (const float*)d_in[14];
    const float* Wv_root  = (const float*)d_in[15];

    const int* srcA = ei;
    const int* dstA = ei + NE;

    char* w8 = (char*)d_ws;
    int2* csr   = (int2*)w8;                 // 12.8 MB
    int* deg    = (int*)(csr + NE);          // 400 KB
    int* off    = deg + NN;
    int* cursor = off + NN;
    int* bsum   = cursor + NN;               // 512 ints
    int* ebase  = bsum + 512;                // 512 ints
    float* A    = (float*)(ebase + 512);     // 12.8 MB  (proj1 / proj2)
    float* H    = A + NW;                    // 12.8 MB  (h1)
    float2* pv  = (float2*)(H + NW);         // 800 KB
    float* pbase = (float*)(pv + NN);        // 400 KB
    float* vbase = pbase + NN;               // 400 KB
    // aliases into A (free after agg2_heads_v2):
    float* pm    = A;
    float* ev    = A + NN;
    float* parts = A + 2 * (size_t)NN;       // 391
    float* scal  = parts + 512;

    const long long* csr64 = (const long long*)csr;

    float* out_p = (float*)d_out;
    float* out_v = out_p + NN;

    const int NB_N   = (NN + 255) / 256;  // 391
    const int NB_E   = (NE + 255) / 256;  // 6250
    const int NB_MM  = NN / 8;            // 12500
    const int NB_W4  = NN / 4;            // 25000 (wave-per-node kernels)
    const int NB_HF  = NN / 32;           // 3125

    // --- CSR build ---
    hipMemsetAsync(deg, 0, NN * sizeof(int), stream);
    hist_k<<<NB_E, 256, 0, stream>>>(dstA, deg);
    block_sum_k<<<NB_N, 256, 0, stream>>>(deg, bsum);
    scan_bsum_k<<<1, 512, 0, stream>>>(bsum, NB_N, ebase);
    scan_write_k<<<NB_N, 256, 0, stream>>>(deg, ebase, off, cursor);
    fill2_k<<<NSLICE * FILL_BPG, 256, 0, stream>>>(srcA, dstA, ew, cursor, csr);

    // --- Layer 1 ---
    matmul_k<64><<<NB_MM, 256, 0, stream>>>(x, Win_rel, A);
    agg_root_relu_v2<64><<<NB_W4, 256, 0, stream>>>(A, x, Win_root, bin_rel,
                                                    csr64, off, deg, H);
    // --- Layer 2 + heads ---
    matmul_k<32><<<NB_MM, 256, 0, stream>>>(H, Wh_rel, A);
    agg2_heads_v2<<<NB_W4, 256, 0, stream>>>(A, H, Wh_root, bh_rel, Wp_rel,
                                             Wp_root, bp, Wv_rel, Wv_root, bv,
                                             csr64, off, deg, pv, pbase, vbase);
    // --- Head aggregation + mask + finalize ---
    heads_final_v2<<<NB_HF, 256, 0, stream>>>(pv, pbase, vbase, csr64, off, deg,
                                              cur, pm, out_v, parts);
    reduce_max_k<<<1, 256, 0, stream>>>(parts, NB_N, scal);
    expsum_k<<<NB_N, 256, 0, stream>>>(pm, scal, ev);
    normalize_k<<<NB_N, 256, 0, stream>>>(ev, scal, out_p);
}